// Round 2
// baseline (402.124 us; speedup 1.0000x reference)
//
#include <hip/hip_runtime.h>

#define Bn 256
#define Sn 4096
#define Fn 64
#define TCOST 0.0003f
#define INIT_CAP 500.0f

// Output layout (floats):
//   equity      : [B, S+1]        offset 0
//   positions   : [B, S+1, 3]     offset B*(S+1)
//   predictions : [B, S]          offset B*(S+1)*4
//   position_sz : [B]             offset B*(S+1)*4 + B*S
#define EQ_OFF   0
#define POS_OFF  (Bn * (Sn + 1))
#define PRED_OFF (Bn * (Sn + 1) * 4)
#define PSZ_OFF  (PRED_OFF + Bn * Sn)

// ---------------------------------------------------------------------------
// Kernel T: transpose gumbel [S, B, 3] -> [B, S, 3] so kernel A can read it
// coalesced. 32x32 element tiles (each element = 3 floats) via LDS.
// ---------------------------------------------------------------------------
__global__ __launch_bounds__(256) void gumbel_transpose(
    const float* __restrict__ gin,   // [S, B, 3]
    float* __restrict__ gout)        // [B, S, 3]
{
    __shared__ float tile[32 * 97];  // [i(s)][j*3+c], stride 97 breaks conflicts
    int s0 = (blockIdx.x & 127) * 32;   // S/32 = 128 tiles along s
    int b0 = (blockIdx.x >> 7) * 32;    // B/32 = 8 tiles along b

    // load: rows of 96 contiguous floats per s
    for (int idx = threadIdx.x; idx < 32 * 96; idx += 256) {
        int i = idx / 96;            // s offset
        int rem = idx - i * 96;      // j*3+c
        tile[i * 97 + rem] = gin[(size_t)(s0 + i) * (Bn * 3) + b0 * 3 + rem];
    }
    __syncthreads();
    // store: rows of 96 contiguous floats per b
    for (int idx = threadIdx.x; idx < 32 * 96; idx += 256) {
        int j = idx / 96;            // b offset
        int rem = idx - j * 96;      // i*3+c
        int i = rem / 3;
        int c = rem - i * 3;
        gout[(size_t)(b0 + j) * (Sn * 3) + (size_t)(s0 + i) * 3 + c] =
            tile[i * 97 + j * 3 + c];
    }
}

// ---------------------------------------------------------------------------
// Kernel A: coalesced feature matvec (16 lanes per row, shuffle reduce) +
// gumbel-softmax epilogue (one row per thread via LDS handoff).
// ---------------------------------------------------------------------------
__global__ __launch_bounds__(256) void trishot_fwd(
    const float* __restrict__ feat,     // [B, S, F]
    const float* __restrict__ w,        // [F]
    const float* __restrict__ p_lt, const float* __restrict__ p_st,
    const float* __restrict__ p_bps, const float* __restrict__ p_cs,
    const float* __restrict__ p_vi, const float* __restrict__ p_vct,
    const float* __restrict__ p_vst,
    const float* __restrict__ gt,       // [B, S, 3] (transposed gumbel)
    float* __restrict__ out)
{
    __shared__ float xs[256];
    __shared__ float m0s[256], v0s[256], d0s[256], r0s[256];

    int t = threadIdx.x;
    int R0 = blockIdx.x * 256;          // first row of this tile
    int g = t >> 4;                     // row-within-pass 0..15
    int l = t & 15;                     // lane-in-row 0..15

    float4 wv = ((const float4*)w)[l];  // this lane's weight chunk

    // Phase 1: dot products, 16 rows per pass, 16 passes.
    // Per wave per load: 64 lanes x 16B = 1024B contiguous (4 rows).
#pragma unroll
    for (int q = 0; q < 16; q++) {
        int row = R0 + q * 16 + g;
        float4 fv = ((const float4*)feat)[(size_t)row * 16 + l];
        float partial = fmaf(fv.x, wv.x,
                        fmaf(fv.y, wv.y,
                        fmaf(fv.z, wv.z, fv.w * wv.w)));
        partial += __shfl_xor(partial, 1, 64);
        partial += __shfl_xor(partial, 2, 64);
        partial += __shfl_xor(partial, 4, 64);
        partial += __shfl_xor(partial, 8, 64);
        if (l == 0) {
            int rr = q * 16 + g;
            xs[rr]  = partial;
            m0s[rr] = fv.x;   // feat[row*64 + 0] = momentum
            v0s[rr] = fv.y;   // vix
            d0s[rr] = fv.z;   // vix change
            r0s[rr] = fv.w;   // mret
        }
    }
    __syncthreads();

    // Phase 2: one row per thread, all accesses coalesced.
    int r = R0 + t;
    int b = r >> 12;                    // S = 4096 = 2^12
    int s = r & (Sn - 1);

    const float LT = *p_lt, ST = *p_st, BPS = *p_bps, CS = *p_cs,
                VI = *p_vi, VCT = *p_vct, VST = *p_vst;

    float x = xs[t];
    float p = 1.0f / (1.0f + __expf(-x));
    float mom = m0s[t], vix = v0s[t], dvix = d0s[t], mret = r0s[t];

    float ss = fabsf(p - 0.5f) * 2.0f;
    bool collapse = (dvix < -VCT) && (vix < 30.0f);
    bool spike    = (dvix >  VST) && (vix > 20.0f);
    float psz = fminf(fmaxf(BPS + CS * ss, 0.2f), 1.0f);
    if (collapse || spike) psz *= (1.0f + VI);

    bool lp = ((p >= LT) && (mom > 0.0f)) || collapse;
    bool sp = ((p <= ST) && (mom < 0.0f)) || spike;
    float l0 = lp ? 1.0f : -10.0f;
    float l1 = sp ? 1.0f : -10.0f;
    float l2 = (!lp && !sp) ? 1.0f : -10.0f;

    const float* gg = gt + (size_t)r * 3;   // coalesced: 12B per lane
    float g0 = gg[0], g1 = gg[1], g2 = gg[2];
    float z0 = l0 + g0, z1 = l1 + g1, z2 = l2 + g2;
    float zm = fmaxf(z0, fmaxf(z1, z2));
    float e0 = __expf(z0 - zm), e1 = __expf(z1 - zm), e2 = __expf(z2 - zm);
    float inv = 1.0f / (e0 + e1 + e2);
    float q0 = e0 * inv, q1 = e1 * inv, q2 = e2 * inv;

    // predictions [B,S]
    out[PRED_OFF + r] = p;

    // positions [B, S+1, 3] at row s+1
    size_t prow = ((size_t)b * (Sn + 1) + s + 1) * 3;
    float* pos = out + POS_OFF;
    pos[prow + 0] = q0;
    pos[prow + 1] = q1;
    pos[prow + 2] = q2;

    // stage ret_part into equity cell [b][s+1] (kernel B overwrites with eq)
    out[EQ_OFF + (size_t)b * (Sn + 1) + s + 1] = psz * (q0 - q1) * mret;

    if (s == 0) {
        size_t p0row = (size_t)b * (Sn + 1) * 3;
        pos[p0row + 0] = 0.0f;
        pos[p0row + 1] = 0.0f;
        pos[p0row + 2] = 1.0f;
    }
    if (s == Sn - 1) {
        out[PSZ_OFF + b] = psz;   // last-step position size
    }
}

// ---------------------------------------------------------------------------
// Kernel B: one block per batch element; parallel prefix-product for equity.
// ---------------------------------------------------------------------------
#define CH 16   // timesteps per thread (256 threads * 16 = 4096)
__global__ __launch_bounds__(256) void trishot_scan(float* __restrict__ out)
{
    int b = blockIdx.x;
    int j = threadIdx.x;

    float* eq = out + EQ_OFF + (size_t)b * (Sn + 1);
    const float* pos = out + POS_OFF + (size_t)b * (Sn + 1) * 3;

    int t0 = j * CH;
    float prev0 = pos[(size_t)t0 * 3 + 0];
    float prev1 = pos[(size_t)t0 * 3 + 1];
    float prev2 = pos[(size_t)t0 * 3 + 2];

    float f[CH];
    float lprod = 1.0f;
#pragma unroll
    for (int i = 0; i < CH; i++) {
        size_t ci = (size_t)(t0 + i + 1) * 3;
        float c0 = pos[ci + 0], c1 = pos[ci + 1], c2 = pos[ci + 2];
        float pc = fabsf(c0 - prev0) + fabsf(c1 - prev1) + fabsf(c2 - prev2);
        float rp = eq[t0 + i + 1];   // staged ret_part
        float fac = 1.0f + rp - pc * TCOST;
        f[i] = fac;
        lprod *= fac;
        prev0 = c0; prev1 = c1; prev2 = c2;
    }

    __shared__ float sc[256];
    sc[j] = lprod;
    __syncthreads();
    // Hillis-Steele inclusive scan (product)
#pragma unroll
    for (int off = 1; off < 256; off <<= 1) {
        float mine = sc[j];
        float other = (j >= off) ? sc[j - off] : 1.0f;
        __syncthreads();
        sc[j] = mine * other;
        __syncthreads();
    }

    float eqv = INIT_CAP * ((j > 0) ? sc[j - 1] : 1.0f);
#pragma unroll
    for (int i = 0; i < CH; i++) {
        eqv *= f[i];
        eq[t0 + i + 1] = eqv;
    }
    if (j == 0) eq[0] = INIT_CAP;
}

extern "C" void kernel_launch(void* const* d_in, const int* in_sizes, int n_in,
                              void* d_out, int out_size, void* d_ws, size_t ws_size,
                              hipStream_t stream) {
    const float* feat   = (const float*)d_in[0];
    const float* w      = (const float*)d_in[1];
    const float* lt     = (const float*)d_in[2];
    const float* st     = (const float*)d_in[3];
    const float* bps    = (const float*)d_in[4];
    const float* cs     = (const float*)d_in[5];
    const float* vi     = (const float*)d_in[6];
    const float* vct    = (const float*)d_in[7];
    const float* vst    = (const float*)d_in[8];
    const float* gumbel = (const float*)d_in[9];
    float* out = (float*)d_out;
    float* gt  = (float*)d_ws;   // 12.6 MB transposed gumbel (ws is ~1 GB)

    gumbel_transpose<<<128 * 8, 256, 0, stream>>>(gumbel, gt);
    trishot_fwd<<<(Bn * Sn) / 256, 256, 0, stream>>>(
        feat, w, lt, st, bps, cs, vi, vct, vst, gt, out);
    trishot_scan<<<Bn, 256, 0, stream>>>(out);
}

// Round 3
// 396.591 us; speedup vs baseline: 1.0140x; 1.0140x over previous
//
#include <hip/hip_runtime.h>

#define Bn 256
#define Sn 4096
#define Fn 64
#define TCOST 0.0003f
#define INIT_CAP 500.0f

// Output layout (floats):
//   equity      : [B, S+1]        offset 0
//   positions   : [B, S+1, 3]     offset B*(S+1)
//   predictions : [B, S]          offset B*(S+1)*4
//   position_sz : [B]             offset B*(S+1)*4 + B*S
#define EQ_OFF   0
#define POS_OFF  (Bn * (Sn + 1))
#define PRED_OFF (Bn * (Sn + 1) * 4)
#define PSZ_OFF  (PRED_OFF + Bn * Sn)

// ---------------------------------------------------------------------------
// Kernel T: transpose gumbel [S, B, 3] -> [B, S, 3] so the fused kernel can
// read it coalesced. 32x32 element tiles (each element = 3 floats) via LDS.
// ---------------------------------------------------------------------------
__global__ __launch_bounds__(256) void gumbel_transpose(
    const float* __restrict__ gin,   // [S, B, 3]
    float* __restrict__ gout)        // [B, S, 3]
{
    __shared__ float tile[32 * 97];  // [i(s)][j*3+c], stride 97 breaks conflicts
    int s0 = (blockIdx.x & 127) * 32;   // S/32 = 128 tiles along s
    int b0 = (blockIdx.x >> 7) * 32;    // B/32 = 8 tiles along b

    for (int idx = threadIdx.x; idx < 32 * 96; idx += 256) {
        int i = idx / 96;            // s offset
        int rem = idx - i * 96;      // j*3+c
        tile[i * 97 + rem] = gin[(size_t)(s0 + i) * (Bn * 3) + b0 * 3 + rem];
    }
    __syncthreads();
    for (int idx = threadIdx.x; idx < 32 * 96; idx += 256) {
        int j = idx / 96;            // b offset
        int rem = idx - j * 96;      // i*3+c
        int i = rem / 3;
        int c = rem - i * 3;
        gout[(size_t)(b0 + j) * (Sn * 3) + (size_t)(s0 + i) * 3 + c] =
            tile[i * 97 + j * 3 + c];
    }
}

// ---------------------------------------------------------------------------
// Fused kernel: one block (1024 threads) per batch element b.
//   Phase 1 (x4 chunks of 1024 steps): coalesced feature dot (16 lanes/row,
//     shuffle reduce) -> LDS.
//   Phase 2a: per-step epilogue, coalesced; probs -> LDS + global pos/pred.
//   Phase 2b: per-step factor = 1 + ret - TC*|dpos| -> LDS.
//   Phase 3: 1024-wide Hillis-Steele prefix product -> equity, one pass.
// No intermediate global round trips.
// ---------------------------------------------------------------------------
__global__ __launch_bounds__(1024) void trishot_fused(
    const float* __restrict__ feat,     // [B, S, F]
    const float* __restrict__ w,        // [F]
    const float* __restrict__ p_lt, const float* __restrict__ p_st,
    const float* __restrict__ p_bps, const float* __restrict__ p_cs,
    const float* __restrict__ p_vi, const float* __restrict__ p_vct,
    const float* __restrict__ p_vst,
    const float* __restrict__ gt,       // [B, S, 3] (transposed gumbel)
    float* __restrict__ out)
{
    __shared__ float qL[(Sn + 1) * 3];   // probs, q[0] = initial pos (0,0,1)
    __shared__ float facL[Sn];           // per-step equity factors
    __shared__ float xs[1024];           // dot results for current chunk
    __shared__ float m0s[1024], v0s[1024], d0s[1024], r0s[1024];
    __shared__ float scanL[1024];

    int b = blockIdx.x;
    int t = threadIdx.x;
    int g = t >> 4;                      // row group 0..63
    int l = t & 15;                      // lane in row 0..15

    const float LT = *p_lt, ST = *p_st, BPS = *p_bps, CS = *p_cs,
                VI = *p_vi, VCT = *p_vct, VST = *p_vst;

    float4 wv = ((const float4*)w)[l];

    if (t == 0) { qL[0] = 0.0f; qL[1] = 0.0f; qL[2] = 1.0f; }

    float* pos = out + POS_OFF;

    for (int c = 0; c < 4; c++) {
        // ---- Phase 1: dots for 1024 steps (64 rows/pass x 16 passes) ----
#pragma unroll
        for (int q = 0; q < 16; q++) {
            int i = q * 64 + g;                       // local step 0..1023
            size_t row = (size_t)b * Sn + c * 1024 + i;
            float4 fv = ((const float4*)feat)[row * 16 + l];
            float partial = fmaf(fv.x, wv.x,
                            fmaf(fv.y, wv.y,
                            fmaf(fv.z, wv.z, fv.w * wv.w)));
            partial += __shfl_xor(partial, 1, 64);
            partial += __shfl_xor(partial, 2, 64);
            partial += __shfl_xor(partial, 4, 64);
            partial += __shfl_xor(partial, 8, 64);
            if (l == 0) {
                xs[i]  = partial;
                m0s[i] = fv.x;   // momentum
                v0s[i] = fv.y;   // vix
                d0s[i] = fv.z;   // vix change
                r0s[i] = fv.w;   // mret
            }
        }
        __syncthreads();

        // ---- Phase 2a: epilogue, one step per thread, coalesced ----
        int s = c * 1024 + t;
        float x = xs[t];
        float p = 1.0f / (1.0f + __expf(-x));
        float mom = m0s[t], vix = v0s[t], dvix = d0s[t], mret = r0s[t];

        float ss = fabsf(p - 0.5f) * 2.0f;
        bool collapse = (dvix < -VCT) && (vix < 30.0f);
        bool spike    = (dvix >  VST) && (vix > 20.0f);
        float psz = fminf(fmaxf(BPS + CS * ss, 0.2f), 1.0f);
        if (collapse || spike) psz *= (1.0f + VI);

        bool lp = ((p >= LT) && (mom > 0.0f)) || collapse;
        bool sp = ((p <= ST) && (mom < 0.0f)) || spike;
        float l0 = lp ? 1.0f : -10.0f;
        float l1 = sp ? 1.0f : -10.0f;
        float l2 = (!lp && !sp) ? 1.0f : -10.0f;

        const float* gg = gt + ((size_t)b * Sn + s) * 3;
        float z0 = l0 + gg[0], z1 = l1 + gg[1], z2 = l2 + gg[2];
        float zm = fmaxf(z0, fmaxf(z1, z2));
        float e0 = __expf(z0 - zm), e1 = __expf(z1 - zm), e2 = __expf(z2 - zm);
        float inv = 1.0f / (e0 + e1 + e2);
        float q0 = e0 * inv, q1 = e1 * inv, q2 = e2 * inv;

        qL[(s + 1) * 3 + 0] = q0;
        qL[(s + 1) * 3 + 1] = q1;
        qL[(s + 1) * 3 + 2] = q2;

        out[PRED_OFF + (size_t)b * Sn + s] = p;
        size_t prow = ((size_t)b * (Sn + 1) + s + 1) * 3;
        pos[prow + 0] = q0;
        pos[prow + 1] = q1;
        pos[prow + 2] = q2;
        if (s == Sn - 1) out[PSZ_OFF + b] = psz;

        float rp = psz * (q0 - q1) * mret;
        __syncthreads();

        // ---- Phase 2b: factor needs previous step's probs ----
        float pm0 = qL[s * 3 + 0], pm1 = qL[s * 3 + 1], pm2 = qL[s * 3 + 2];
        float pc = fabsf(q0 - pm0) + fabsf(q1 - pm1) + fabsf(q2 - pm2);
        facL[s] = 1.0f + rp - pc * TCOST;
        __syncthreads();   // xs/m0s/... reused next chunk
    }

    // ---- Phase 3: prefix product over 4096 factors ----
    float f0 = facL[4 * t + 0];
    float f1 = facL[4 * t + 1];
    float f2 = facL[4 * t + 2];
    float f3 = facL[4 * t + 3];
    float lprod = ((f0 * f1) * (f2 * f3));
    scanL[t] = lprod;
    __syncthreads();
#pragma unroll
    for (int off = 1; off < 1024; off <<= 1) {
        float mine = scanL[t];
        float other = (t >= off) ? scanL[t - off] : 1.0f;
        __syncthreads();
        scanL[t] = mine * other;
        __syncthreads();
    }

    float* eq = out + EQ_OFF + (size_t)b * (Sn + 1);
    float eqv = INIT_CAP * ((t > 0) ? scanL[t - 1] : 1.0f);
    eqv *= f0; eq[4 * t + 1] = eqv;
    eqv *= f1; eq[4 * t + 2] = eqv;
    eqv *= f2; eq[4 * t + 3] = eqv;
    eqv *= f3; eq[4 * t + 4] = eqv;

    if (t == 0) {
        eq[0] = INIT_CAP;
        size_t p0row = (size_t)b * (Sn + 1) * 3;
        pos[p0row + 0] = 0.0f;
        pos[p0row + 1] = 0.0f;
        pos[p0row + 2] = 1.0f;
    }
}

extern "C" void kernel_launch(void* const* d_in, const int* in_sizes, int n_in,
                              void* d_out, int out_size, void* d_ws, size_t ws_size,
                              hipStream_t stream) {
    const float* feat   = (const float*)d_in[0];
    const float* w      = (const float*)d_in[1];
    const float* lt     = (const float*)d_in[2];
    const float* st     = (const float*)d_in[3];
    const float* bps    = (const float*)d_in[4];
    const float* cs     = (const float*)d_in[5];
    const float* vi     = (const float*)d_in[6];
    const float* vct    = (const float*)d_in[7];
    const float* vst    = (const float*)d_in[8];
    const float* gumbel = (const float*)d_in[9];
    float* out = (float*)d_out;
    float* gt  = (float*)d_ws;   // 12.6 MB transposed gumbel

    gumbel_transpose<<<128 * 8, 256, 0, stream>>>(gumbel, gt);
    trishot_fused<<<Bn, 1024, 0, stream>>>(
        feat, w, lt, st, bps, cs, vi, vct, vst, gt, out);
}